// Round 4
// baseline (813.550 us; speedup 1.0000x reference)
//
#include <hip/hip_runtime.h>
#include <hip/hip_bf16.h>

#define D_MODEL 768
#define D_STATE 16
#define D_INNER 1536
#define DT_RANK 48
#define BATCH   4
#define SEQ     2048
#define ROWS    (BATCH*SEQ)   // 8192
#define NCHUNK  8
#define CHUNK   (SEQ/NCHUNK)  // 256

typedef __attribute__((ext_vector_type(8)))  short  short8;
typedef __attribute__((ext_vector_type(4)))  float  f32x4;
typedef __attribute__((ext_vector_type(2)))  float  f32x2;
typedef __attribute__((ext_vector_type(4)))  unsigned short us4;

static __device__ __forceinline__ unsigned short f2bf(float f) {
  union { float f; unsigned u; } v; v.f = f;
  unsigned r = v.u + 0x7fffu + ((v.u >> 16) & 1u);
  return (unsigned short)(r >> 16);
}
static __device__ __forceinline__ float bf2f(unsigned short u) {
  union { unsigned u; float f; } v; v.u = ((unsigned)u) << 16;
  return v.f;
}

// DPP-based add of lane-permuted value (VALU pipe, no LDS traffic)
template<int CTRL>
static __device__ __forceinline__ float dpp_add(float x) {
  union { float f; int i; } v; v.f = x;
  int m = __builtin_amdgcn_update_dpp(0, v.i, CTRL, 0xF, 0xF, true);
  union { int i; float f; } r; r.i = m;
  return x + r.f;
}
// sum over each 16-lane group (n = lane & 15)
static __device__ __forceinline__ float reduce16(float y) {
  y = dpp_add<0xB1>(y);   // quad_perm [1,0,3,2]  (xor 1)
  y = dpp_add<0x4E>(y);   // quad_perm [2,3,0,1]  (xor 2)
  y = dpp_add<0x141>(y);  // row_half_mirror      (crosses quads within 8)
  y = dpp_add<0x140>(y);  // row_mirror           (crosses 8-boundary)
  return y;
}

// ---------------- LayerNorm -> bf16 ----------------
__global__ __launch_bounds__(256)
void ln_kernel(const float* __restrict__ x, const float* __restrict__ gamma,
               const float* __restrict__ beta, unsigned short* __restrict__ xn_bf) {
  int row  = blockIdx.x * 4 + (threadIdx.x >> 6);
  int lane = threadIdx.x & 63;
  const float* xr = x + (size_t)row * D_MODEL;
  f32x4 v[3];
  float s = 0.f, s2 = 0.f;
#pragma unroll
  for (int c = 0; c < 3; c++) {
    v[c] = *reinterpret_cast<const f32x4*>(&xr[c*256 + lane*4]);
#pragma unroll
    for (int i = 0; i < 4; i++) { s += v[c][i]; s2 += v[c][i]*v[c][i]; }
  }
#pragma unroll
  for (int off = 1; off < 64; off <<= 1) {
    s  += __shfl_xor(s,  off);
    s2 += __shfl_xor(s2, off);
  }
  float mu   = s * (1.0f/768.0f);
  float var  = s2 * (1.0f/768.0f) - mu*mu;
  float rstd = rsqrtf(var + 1e-5f);
#pragma unroll
  for (int c = 0; c < 3; c++) {
    us4 o;
#pragma unroll
    for (int i = 0; i < 4; i++) {
      int g = c*256 + lane*4 + i;
      float xn = (v[c][i]-mu)*rstd*gamma[g] + beta[g];
      o[i] = f2bf(xn);
    }
    *reinterpret_cast<us4*>(&xn_bf[(size_t)row*D_MODEL + c*256 + lane*4]) = o;
  }
}

// ---------------- casts ----------------
__global__ void cast_bf(const float* __restrict__ in, unsigned short* __restrict__ out, int n) {
  int i = blockIdx.x * blockDim.x + threadIdx.x;
  if (i < n) out[i] = f2bf(in[i]);
}

// W_dt (1536 x 48) -> bf16 padded to (1536 x 64)
__global__ void cast_wdt(const float* __restrict__ wdt, unsigned short* __restrict__ out) {
  int i = blockIdx.x * blockDim.x + threadIdx.x;
  if (i >= D_INNER*64) return;
  int r = i >> 6, c = i & 63;
  out[i] = (c < DT_RANK) ? f2bf(wdt[r*DT_RANK + c]) : (unsigned short)0;
}

// dt_lo = x_dbl[:, :48] -> bf16 padded to (ROWS x 64)
__global__ void cast_dtlo(const float* __restrict__ xdbl, unsigned short* __restrict__ out) {
  int i = blockIdx.x * blockDim.x + threadIdx.x;
  if (i >= ROWS*64) return;
  int r = i >> 6, c = i & 63;
  out[i] = (c < DT_RANK) ? f2bf(xdbl[(size_t)r*80 + c]) : (unsigned short)0;
}

// ---------------- GEMM: C[M,N] = A[M,K] @ B[N,K]^T  (bf16 in) ----------------
#define EPI_STORE_F32     0   // C fp32
#define EPI_SOFTPLUS_BF16 1   // O1 bf16 = softplus(acc + bias)
#define EPI_ACCUM_F32     2   // C fp32 +=
#define EPI_SPLIT_BF16    3   // O1/O2 bf16 halves at N split 1536

template<int EPI>
__global__ __launch_bounds__(256, 2)
void gemm_bt(const unsigned short* __restrict__ A,
             const unsigned short* __restrict__ B,
             float* __restrict__ C,
             unsigned short* __restrict__ O1,
             unsigned short* __restrict__ O2,
             const float* __restrict__ bias,
             int M, int N, int K) {
  constexpr int LDT = 40;                 // 32 + 8 pad bf16 elems (80B rows)
  __shared__ unsigned short As[128*LDT];
  __shared__ unsigned short Bs[128*LDT];
  const int tid  = threadIdx.x;
  const int lane = tid & 63;
  const int wave = tid >> 6;
  const int wr = wave >> 1, wc = wave & 1; // 2x2 waves, 64x64 each
  const int m0 = blockIdx.x * 128;
  const int n0 = blockIdx.y * 128;
  const int srow = tid >> 2;               // 0..63
  const int scol = (tid & 3) * 8;          // 0,8,16,24

  f32x4 acc[4][4];
#pragma unroll
  for (int i = 0; i < 4; i++)
#pragma unroll
    for (int j = 0; j < 4; j++) acc[i][j] = (f32x4){0.f,0.f,0.f,0.f};

  const int fr = lane & 15;
  const int fk = (lane >> 4) * 8;

  for (int k0 = 0; k0 < K; k0 += 32) {
    __syncthreads();
#pragma unroll
    for (int h = 0; h < 2; h++) {
      int r = srow + h*64;
      {
        const short8 v = *reinterpret_cast<const short8*>(A + (size_t)(m0 + r)*K + k0 + scol);
        *reinterpret_cast<short8*>(&As[r*LDT + scol]) = v;
      }
      {
        short8 v = (short8){0,0,0,0,0,0,0,0};
        int n = n0 + r;
        if (n < N) v = *reinterpret_cast<const short8*>(B + (size_t)n*K + k0 + scol);
        *reinterpret_cast<short8*>(&Bs[r*LDT + scol]) = v;
      }
    }
    __syncthreads();
    short8 aF[4], bF[4];
#pragma unroll
    for (int mi = 0; mi < 4; mi++)
      aF[mi] = *reinterpret_cast<const short8*>(&As[(wr*64 + mi*16 + fr)*LDT + fk]);
#pragma unroll
    for (int ni = 0; ni < 4; ni++)
      bF[ni] = *reinterpret_cast<const short8*>(&Bs[(wc*64 + ni*16 + fr)*LDT + fk]);
#pragma unroll
    for (int mi = 0; mi < 4; mi++)
#pragma unroll
      for (int ni = 0; ni < 4; ni++)
        acc[mi][ni] = __builtin_amdgcn_mfma_f32_16x16x32_bf16(aF[mi], bF[ni], acc[mi][ni], 0, 0, 0);
  }

  const int cr = (lane >> 4) * 4;
  const int cc = lane & 15;
#pragma unroll
  for (int mi = 0; mi < 4; mi++) {
#pragma unroll
    for (int ni = 0; ni < 4; ni++) {
      int gn = n0 + wc*64 + ni*16 + cc;
      if (gn >= N) continue;
      int gmb = m0 + wr*64 + mi*16 + cr;
#pragma unroll
      for (int j = 0; j < 4; j++) {
        float v = acc[mi][ni][j];
        size_t row = (size_t)(gmb + j);
        if constexpr (EPI == EPI_SOFTPLUS_BF16) {
          v += bias[gn];
          float sp = fmaxf(v, 0.0f) + log1pf(expf(-fabsf(v)));
          O1[row*N + gn] = f2bf(sp);
        } else if constexpr (EPI == EPI_SPLIT_BF16) {
          if (gn < D_INNER) O1[row*D_INNER + gn] = f2bf(v);
          else              O2[row*D_INNER + (gn - D_INNER)] = f2bf(v);
        } else if constexpr (EPI == EPI_ACCUM_F32) {
          C[row*N + gn] += v;
        } else {
          C[row*N + gn] = v;
        }
      }
    }
  }
}

// ---------------- GLU GEMM fused with sigmoid gate: out = x + sigmoid(g)*v ----------------
__global__ __launch_bounds__(256, 2)
void gemm_glu(const unsigned short* __restrict__ A,      // xn_bf [ROWS][768]
              const unsigned short* __restrict__ B,      // Wglu_bf [1536][768]
              const float* __restrict__ bias,            // b_glu [1536]
              const float* __restrict__ x,               // residual [ROWS][768]
              float* __restrict__ out) {
  constexpr int LDT = 40;
  constexpr int K = D_MODEL;
  __shared__ unsigned short As[128*LDT];
  __shared__ unsigned short Bg[128*LDT];
  __shared__ unsigned short Bv[128*LDT];
  const int tid  = threadIdx.x;
  const int lane = tid & 63;
  const int wave = tid >> 6;
  const int wr = wave >> 1, wc = wave & 1;
  const int m0 = blockIdx.x * 128;
  const int n0 = blockIdx.y * 128;        // gate col base (0..640)
  const int srow = tid >> 2;
  const int scol = (tid & 3) * 8;

  f32x4 ag[4][4], av[4][4];
#pragma unroll
  for (int i = 0; i < 4; i++)
#pragma unroll
    for (int j = 0; j < 4; j++) { ag[i][j] = (f32x4){0,0,0,0}; av[i][j] = (f32x4){0,0,0,0}; }

  const int fr = lane & 15;
  const int fk = (lane >> 4) * 8;

  for (int k0 = 0; k0 < K; k0 += 32) {
    __syncthreads();
#pragma unroll
    for (int h = 0; h < 2; h++) {
      int r = srow + h*64;
      *reinterpret_cast<short8*>(&As[r*LDT + scol]) =
          *reinterpret_cast<const short8*>(A + (size_t)(m0 + r)*K + k0 + scol);
      *reinterpret_cast<short8*>(&Bg[r*LDT + scol]) =
          *reinterpret_cast<const short8*>(B + (size_t)(n0 + r)*K + k0 + scol);
      *reinterpret_cast<short8*>(&Bv[r*LDT + scol]) =
          *reinterpret_cast<const short8*>(B + (size_t)(n0 + D_MODEL + r)*K + k0 + scol);
    }
    __syncthreads();
    short8 aF[4], gF[4], vF[4];
#pragma unroll
    for (int mi = 0; mi < 4; mi++)
      aF[mi] = *reinterpret_cast<const short8*>(&As[(wr*64 + mi*16 + fr)*LDT + fk]);
#pragma unroll
    for (int ni = 0; ni < 4; ni++) {
      gF[ni] = *reinterpret_cast<const short8*>(&Bg[(wc*64 + ni*16 + fr)*LDT + fk]);
      vF[ni] = *reinterpret_cast<const short8*>(&Bv[(wc*64 + ni*16 + fr)*LDT + fk]);
    }
#pragma unroll
    for (int mi = 0; mi < 4; mi++)
#pragma unroll
      for (int ni = 0; ni < 4; ni++) {
        ag[mi][ni] = __builtin_amdgcn_mfma_f32_16x16x32_bf16(aF[mi], gF[ni], ag[mi][ni], 0, 0, 0);
        av[mi][ni] = __builtin_amdgcn_mfma_f32_16x16x32_bf16(aF[mi], vF[ni], av[mi][ni], 0, 0, 0);
      }
  }

  const int cr = (lane >> 4) * 4;
  const int cc = lane & 15;
#pragma unroll
  for (int mi = 0; mi < 4; mi++) {
#pragma unroll
    for (int ni = 0; ni < 4; ni++) {
      int gn = n0 + wc*64 + ni*16 + cc;
      int gmb = m0 + wr*64 + mi*16 + cr;
      float bg = bias[gn];
      float bv = bias[gn + D_MODEL];
#pragma unroll
      for (int j = 0; j < 4; j++) {
        float g = ag[mi][ni][j] + bg;
        float v = av[mi][ni][j] + bv;
        size_t idx = (size_t)(gmb + j)*D_MODEL + gn;
        out[idx] = x[idx] + v / (1.0f + __expf(-g));
      }
    }
  }
}

// ---------------- conv4 + SiLU (bf16 in -> bf16 u) ----------------
__global__ __launch_bounds__(256)
void conv_silu(const unsigned short* __restrict__ xm, const float* __restrict__ cw,
               const float* __restrict__ cb, unsigned short* __restrict__ u_bf) {
  int idx = blockIdx.x * blockDim.x + threadIdx.x;
  if (idx >= ROWS * D_INNER) return;
  int d   = idx % D_INNER;
  int row = idx / D_INNER;        // b*SEQ + l
  int l   = row % SEQ;
  float acc = cb[d];
#pragma unroll
  for (int k = 0; k < 4; k++) {
    int t = l - 3 + k;
    if (t >= 0) acc += cw[d*4 + k] * bf2f(xm[(size_t)(row - 3 + k)*D_INNER + d]);
  }
  float s  = 1.0f / (1.0f + __expf(-acc));
  u_bf[idx] = f2bf(acc * s);
}

// ================= chunked selective scan (no LDS, no barriers) =================
// Each (b,d,n) is an independent scalar recurrence h = a*h + x,
// a = exp(dt*A[d][n]), x = dt*u*B_t[n].  8 chunks of 256 steps.
// Layout: lane = (dl,n); dt/u broadcast across 16 lanes; B/C coalesced dwords;
// y-reduction over n via DPP (VALU), z/silu/store only on n==0 lanes.

// Phase 1: per-(b,d,n,chunk) affine composition: P = prod(a), q = zero-state response.
__global__ __launch_bounds__(256)
void scan_part1(const unsigned short* __restrict__ dt_bf,
                const unsigned short* __restrict__ u_bf,
                const float* __restrict__ xdbl, const float* __restrict__ A_log,
                float* __restrict__ Pv, float* __restrict__ Qv) {
  const int tid  = threadIdx.x;
  const int lane = tid & 63;
  const int wv   = tid >> 6;
  const int b    = blockIdx.y;
  const int c    = blockIdx.z;
  const int d0   = blockIdx.x * 16;
  const int dl   = wv*4 + (lane >> 4);   // channel within block
  const int n    = lane & 15;            // state index
  const int d    = d0 + dl;
  const float Aa = -__expf(A_log[d*D_STATE + n]);
  float P = 1.f, q = 0.f;
  const size_t rowbase = (size_t)b * SEQ + (size_t)c * CHUNK;

#pragma unroll 4
  for (int t = 0; t < CHUNK; t++) {
    size_t row = rowbase + t;
    float dtv = bf2f(dt_bf[row*D_INNER + d]);
    float uv  = bf2f(u_bf[row*D_INNER + d]);
    float Bv  = xdbl[row*80 + DT_RANK + n];
    float a   = __expf(dtv * Aa);
    q = fmaf(a, q, dtv * uv * Bv);
    P *= a;
  }
  size_t idx = (((size_t)b*D_INNER + d)*D_STATE + n)*NCHUNK + c;
  Pv[idx] = P;
  Qv[idx] = q;
}

// Phase 2: sequential combine across chunks -> initial state per chunk.
__global__ __launch_bounds__(256)
void scan_combine(const float* __restrict__ Pv, const float* __restrict__ Qv,
                  float* __restrict__ H0) {
  int idx = blockIdx.x * 256 + threadIdx.x;   // (b,d,n)
  if (idx >= BATCH*D_INNER*D_STATE) return;
  float h = 0.f;
  size_t base = (size_t)idx * NCHUNK;
#pragma unroll
  for (int c = 0; c < NCHUNK; c++) {
    H0[base + c] = h;
    h = fmaf(Pv[base + c], h, Qv[base + c]);
  }
}

// Phase 3: re-walk each chunk from its initial state; y + gating fused.
__global__ __launch_bounds__(256)
void scan_part3(const unsigned short* __restrict__ dt_bf,
                const unsigned short* __restrict__ u_bf,
                const unsigned short* __restrict__ z_bf,
                const float* __restrict__ xdbl, const float* __restrict__ A_log,
                const float* __restrict__ Dp, const float* __restrict__ H0,
                unsigned short* __restrict__ y_bf) {
  const int tid  = threadIdx.x;
  const int lane = tid & 63;
  const int wv   = tid >> 6;
  const int b    = blockIdx.y;
  const int c    = blockIdx.z;
  const int d0   = blockIdx.x * 16;
  const int dl   = wv*4 + (lane >> 4);
  const int n    = lane & 15;
  const int d    = d0 + dl;
  const float Aa = -__expf(A_log[d*D_STATE + n]);
  const float Dd = Dp[d];
  float h = H0[(((size_t)b*D_INNER + d)*D_STATE + n)*NCHUNK + c];
  const size_t rowbase = (size_t)b * SEQ + (size_t)c * CHUNK;

#pragma unroll 4
  for (int t = 0; t < CHUNK; t++) {
    size_t row = rowbase + t;
    float dtv = bf2f(dt_bf[row*D_INNER + d]);
    float uv  = bf2f(u_bf[row*D_INNER + d]);
    float Bv  = xdbl[row*80 + DT_RANK + n];
    float Cv  = xdbl[row*80 + DT_RANK + D_STATE + n];
    float dA  = __expf(dtv * Aa);
    h = fmaf(dA, h, dtv*uv*Bv);
    float y = reduce16(h * Cv);
    if (n == 0) {
      float z  = bf2f(z_bf[row*D_INNER + d]);
      float sz = z / (1.0f + __expf(-z));
      float yv = (y + uv * Dd) * sz;
      y_bf[row*D_INNER + d] = f2bf(yv);
    }
  }
}

extern "C" void kernel_launch(void* const* d_in, const int* in_sizes, int n_in,
                              void* d_out, int out_size, void* d_ws, size_t ws_size,
                              hipStream_t stream) {
  const float* x      = (const float*)d_in[0];
  const float* lng    = (const float*)d_in[1];
  const float* lnb    = (const float*)d_in[2];
  const float* W_in   = (const float*)d_in[3];
  const float* conv_w = (const float*)d_in[4];
  const float* conv_b = (const float*)d_in[5];
  const float* W_x    = (const float*)d_in[6];
  const float* W_dt   = (const float*)d_in[7];
  const float* b_dt   = (const float*)d_in[8];
  const float* A_log  = (const float*)d_in[9];
  const float* Dp     = (const float*)d_in[10];
  const float* W_out  = (const float*)d_in[11];
  const float* W_glu  = (const float*)d_in[12];
  const float* b_glu  = (const float*)d_in[13];
  float* out = (float*)d_out;

  char* ws = (char*)d_ws;
  size_t off = 0;
  auto alloc = [&](size_t bytes) -> void* {
    void* p = ws + off; off += (bytes + 255) & ~(size_t)255; return p;
  };
  unsigned short* xn_bf   = (unsigned short*)alloc((size_t)ROWS*D_MODEL*2);
  unsigned short* Win_bf  = (unsigned short*)alloc((size_t)2*D_INNER*D_MODEL*2);
  unsigned short* Wx_bf   = (unsigned short*)alloc((size_t)80*D_INNER*2);
  unsigned short* Wdt_bf  = (unsigned short*)alloc((size_t)D_INNER*64*2);
  unsigned short* Wout_bf = (unsigned short*)alloc((size_t)D_MODEL*D_INNER*2);
  unsigned short* Wglu_bf = (unsigned short*)alloc((size_t)2*D_MODEL*D_MODEL*2);
  unsigned short* xm_bf   = (unsigned short*)alloc((size_t)ROWS*D_INNER*2);  // reused as dt_bf
  unsigned short* z_bf    = (unsigned short*)alloc((size_t)ROWS*D_INNER*2);
  unsigned short* u_bf    = (unsigned short*)alloc((size_t)ROWS*D_INNER*2);
  float* x_dbl            = (float*)alloc((size_t)ROWS*80*4);
  unsigned short* dtlo_bf = (unsigned short*)alloc((size_t)ROWS*64*2);
  unsigned short* y_bf    = (unsigned short*)alloc((size_t)ROWS*D_INNER*2);
  float* Pv               = (float*)alloc((size_t)BATCH*D_INNER*D_STATE*NCHUNK*4);
  float* Qv               = (float*)alloc((size_t)BATCH*D_INNER*D_STATE*NCHUNK*4);
  float* H0               = (float*)alloc((size_t)BATCH*D_INNER*D_STATE*NCHUNK*4);
  unsigned short* dt_bf   = xm_bf;   // xm dead after conv_silu; dt born later

  if (off > ws_size) return;  // workspace too small -> clean absmax failure, not a fault

  int n1 = 2*D_INNER*D_MODEL;
  cast_bf<<<(n1+255)/256, 256, 0, stream>>>(W_in, Win_bf, n1);
  int n2 = 80*D_INNER;
  cast_bf<<<(n2+255)/256, 256, 0, stream>>>(W_x, Wx_bf, n2);
  cast_wdt<<<(D_INNER*64+255)/256, 256, 0, stream>>>(W_dt, Wdt_bf);
  int n3 = D_MODEL*D_INNER;
  cast_bf<<<(n3+255)/256, 256, 0, stream>>>(W_out, Wout_bf, n3);
  int n4 = 2*D_MODEL*D_MODEL;
  cast_bf<<<(n4+255)/256, 256, 0, stream>>>(W_glu, Wglu_bf, n4);

  ln_kernel<<<ROWS/4, 256, 0, stream>>>(x, lng, lnb, xn_bf);

  // xz = xn @ W_in^T   (8192 x 3072 x 768) -> split bf16 xm / z
  gemm_bt<EPI_SPLIT_BF16><<<dim3(ROWS/128, (2*D_INNER)/128), 256, 0, stream>>>(
      xn_bf, Win_bf, nullptr, xm_bf, z_bf, nullptr, ROWS, 2*D_INNER, D_MODEL);

  int tc = ROWS*D_INNER;
  conv_silu<<<(tc+255)/256, 256, 0, stream>>>(xm_bf, conv_w, conv_b, u_bf);

  // x_dbl = u @ W_x^T   (8192 x 80 x 1536)
  gemm_bt<EPI_STORE_F32><<<dim3(ROWS/128, 1), 256, 0, stream>>>(
      u_bf, Wx_bf, x_dbl, nullptr, nullptr, nullptr, ROWS, 80, D_INNER);

  cast_dtlo<<<(ROWS*64+255)/256, 256, 0, stream>>>(x_dbl, dtlo_bf);

  // dt = softplus(dt_lo @ W_dt^T + b_dt) -> bf16 (into dead xm region)
  gemm_bt<EPI_SOFTPLUS_BF16><<<dim3(ROWS/128, D_INNER/128), 256, 0, stream>>>(
      dtlo_bf, Wdt_bf, nullptr, dt_bf, nullptr, b_dt, ROWS, D_INNER, 64);

  // chunked scan
  scan_part1<<<dim3(D_INNER/16, BATCH, NCHUNK), 256, 0, stream>>>(
      dt_bf, u_bf, x_dbl, A_log, Pv, Qv);
  scan_combine<<<(BATCH*D_INNER*D_STATE + 255)/256, 256, 0, stream>>>(Pv, Qv, H0);
  scan_part3<<<dim3(D_INNER/16, BATCH, NCHUNK), 256, 0, stream>>>(
      dt_bf, u_bf, z_bf, x_dbl, A_log, Dp, H0, y_bf);

  // out = x + sigmoid(gate)*value   (fused GLU GEMM, 8192 x 768(x2) x 768)
  gemm_glu<<<dim3(ROWS/128, D_MODEL/128), 256, 0, stream>>>(
      xn_bf, Wglu_bf, b_glu, x, out);

  // out += y @ W_out^T   (8192 x 768 x 1536)
  gemm_bt<EPI_ACCUM_F32><<<dim3(ROWS/128, D_MODEL/128), 256, 0, stream>>>(
      y_bf, Wout_bf, out, nullptr, nullptr, nullptr, ROWS, D_MODEL, D_INNER);
}

// Round 5
// 556.348 us; speedup vs baseline: 1.4623x; 1.4623x over previous
//
#include <hip/hip_runtime.h>
#include <hip/hip_bf16.h>

#define D_MODEL 768
#define D_STATE 16
#define D_INNER 1536
#define DT_RANK 48
#define BATCH   4
#define SEQ     2048
#define ROWS    (BATCH*SEQ)   // 8192
#define NCHUNK  8
#define CHUNK   (SEQ/NCHUNK)  // 256

typedef __attribute__((ext_vector_type(8)))  short  short8;
typedef __attribute__((ext_vector_type(4)))  float  f32x4;
typedef __attribute__((ext_vector_type(2)))  float  f32x2;
typedef __attribute__((ext_vector_type(4)))  unsigned short us4;

static __device__ __forceinline__ unsigned short f2bf(float f) {
  union { float f; unsigned u; } v; v.f = f;
  unsigned r = v.u + 0x7fffu + ((v.u >> 16) & 1u);
  return (unsigned short)(r >> 16);
}
static __device__ __forceinline__ float bf2f(unsigned short u) {
  union { unsigned u; float f; } v; v.u = ((unsigned)u) << 16;
  return v.f;
}

// DPP-based add of lane-permuted value (VALU pipe, no LDS traffic)
template<int CTRL>
static __device__ __forceinline__ float dpp_add(float x) {
  union { float f; int i; } v; v.f = x;
  int m = __builtin_amdgcn_update_dpp(0, v.i, CTRL, 0xF, 0xF, true);
  union { int i; float f; } r; r.i = m;
  return x + r.f;
}
// sum over each 16-lane group (n = lane & 15)  [validated round 4]
static __device__ __forceinline__ float reduce16(float y) {
  y = dpp_add<0xB1>(y);   // quad_perm [1,0,3,2]  (xor 1)
  y = dpp_add<0x4E>(y);   // quad_perm [2,3,0,1]  (xor 2)
  y = dpp_add<0x141>(y);  // row_half_mirror
  y = dpp_add<0x140>(y);  // row_mirror
  return y;
}

// ---------------- LayerNorm -> bf16 ----------------
__global__ __launch_bounds__(256)
void ln_kernel(const float* __restrict__ x, const float* __restrict__ gamma,
               const float* __restrict__ beta, unsigned short* __restrict__ xn_bf) {
  int row  = blockIdx.x * 4 + (threadIdx.x >> 6);
  int lane = threadIdx.x & 63;
  const float* xr = x + (size_t)row * D_MODEL;
  f32x4 v[3];
  float s = 0.f, s2 = 0.f;
#pragma unroll
  for (int c = 0; c < 3; c++) {
    v[c] = *reinterpret_cast<const f32x4*>(&xr[c*256 + lane*4]);
#pragma unroll
    for (int i = 0; i < 4; i++) { s += v[c][i]; s2 += v[c][i]*v[c][i]; }
  }
#pragma unroll
  for (int off = 1; off < 64; off <<= 1) {
    s  += __shfl_xor(s,  off);
    s2 += __shfl_xor(s2, off);
  }
  float mu   = s * (1.0f/768.0f);
  float var  = s2 * (1.0f/768.0f) - mu*mu;
  float rstd = rsqrtf(var + 1e-5f);
#pragma unroll
  for (int c = 0; c < 3; c++) {
    us4 o;
#pragma unroll
    for (int i = 0; i < 4; i++) {
      int g = c*256 + lane*4 + i;
      float xn = (v[c][i]-mu)*rstd*gamma[g] + beta[g];
      o[i] = f2bf(xn);
    }
    *reinterpret_cast<us4*>(&xn_bf[(size_t)row*D_MODEL + c*256 + lane*4]) = o;
  }
}

// ---------------- casts ----------------
__global__ void cast_bf(const float* __restrict__ in, unsigned short* __restrict__ out, int n) {
  int i = blockIdx.x * blockDim.x + threadIdx.x;
  if (i < n) out[i] = f2bf(in[i]);
}

// W_dt (1536 x 48) -> bf16 padded to (1536 x 64)
__global__ void cast_wdt(const float* __restrict__ wdt, unsigned short* __restrict__ out) {
  int i = blockIdx.x * blockDim.x + threadIdx.x;
  if (i >= D_INNER*64) return;
  int r = i >> 6, c = i & 63;
  out[i] = (c < DT_RANK) ? f2bf(wdt[r*DT_RANK + c]) : (unsigned short)0;
}

// dt_lo = x_dbl[:, :48] -> bf16 padded to (ROWS x 64)
__global__ void cast_dtlo(const float* __restrict__ xdbl, unsigned short* __restrict__ out) {
  int i = blockIdx.x * blockDim.x + threadIdx.x;
  if (i >= ROWS*64) return;
  int r = i >> 6, c = i & 63;
  out[i] = (c < DT_RANK) ? f2bf(xdbl[(size_t)r*80 + c]) : (unsigned short)0;
}

// ---------------- GEMM: C[M,N] = A[M,K] @ B[N,K]^T  (bf16 in) ----------------
#define EPI_STORE_F32     0   // C fp32
#define EPI_SOFTPLUS_BF16 1   // O1 bf16 = softplus(acc + bias)
#define EPI_ACCUM_F32     2   // C fp32 +=
#define EPI_SPLIT_BF16    3   // O1/O2 bf16 halves at N split 1536

template<int EPI>
__global__ __launch_bounds__(256, 2)
void gemm_bt(const unsigned short* __restrict__ A,
             const unsigned short* __restrict__ B,
             float* __restrict__ C,
             unsigned short* __restrict__ O1,
             unsigned short* __restrict__ O2,
             const float* __restrict__ bias,
             int M, int N, int K) {
  constexpr int LDT = 40;                 // 32 + 8 pad bf16 elems (80B rows)
  __shared__ unsigned short As[128*LDT];
  __shared__ unsigned short Bs[128*LDT];
  const int tid  = threadIdx.x;
  const int lane = tid & 63;
  const int wave = tid >> 6;
  const int wr = wave >> 1, wc = wave & 1; // 2x2 waves, 64x64 each
  const int m0 = blockIdx.x * 128;
  const int n0 = blockIdx.y * 128;
  const int srow = tid >> 2;               // 0..63
  const int scol = (tid & 3) * 8;          // 0,8,16,24

  f32x4 acc[4][4];
#pragma unroll
  for (int i = 0; i < 4; i++)
#pragma unroll
    for (int j = 0; j < 4; j++) acc[i][j] = (f32x4){0.f,0.f,0.f,0.f};

  const int fr = lane & 15;
  const int fk = (lane >> 4) * 8;

  for (int k0 = 0; k0 < K; k0 += 32) {
    __syncthreads();
#pragma unroll
    for (int h = 0; h < 2; h++) {
      int r = srow + h*64;
      {
        const short8 v = *reinterpret_cast<const short8*>(A + (size_t)(m0 + r)*K + k0 + scol);
        *reinterpret_cast<short8*>(&As[r*LDT + scol]) = v;
      }
      {
        short8 v = (short8){0,0,0,0,0,0,0,0};
        int n = n0 + r;
        if (n < N) v = *reinterpret_cast<const short8*>(B + (size_t)n*K + k0 + scol);
        *reinterpret_cast<short8*>(&Bs[r*LDT + scol]) = v;
      }
    }
    __syncthreads();
    short8 aF[4], bF[4];
#pragma unroll
    for (int mi = 0; mi < 4; mi++)
      aF[mi] = *reinterpret_cast<const short8*>(&As[(wr*64 + mi*16 + fr)*LDT + fk]);
#pragma unroll
    for (int ni = 0; ni < 4; ni++)
      bF[ni] = *reinterpret_cast<const short8*>(&Bs[(wc*64 + ni*16 + fr)*LDT + fk]);
#pragma unroll
    for (int mi = 0; mi < 4; mi++)
#pragma unroll
      for (int ni = 0; ni < 4; ni++)
        acc[mi][ni] = __builtin_amdgcn_mfma_f32_16x16x32_bf16(aF[mi], bF[ni], acc[mi][ni], 0, 0, 0);
  }

  const int cr = (lane >> 4) * 4;
  const int cc = lane & 15;
#pragma unroll
  for (int mi = 0; mi < 4; mi++) {
#pragma unroll
    for (int ni = 0; ni < 4; ni++) {
      int gn = n0 + wc*64 + ni*16 + cc;
      if (gn >= N) continue;
      int gmb = m0 + wr*64 + mi*16 + cr;
#pragma unroll
      for (int j = 0; j < 4; j++) {
        float v = acc[mi][ni][j];
        size_t row = (size_t)(gmb + j);
        if constexpr (EPI == EPI_SOFTPLUS_BF16) {
          v += bias[gn];
          float sp = fmaxf(v, 0.0f) + log1pf(expf(-fabsf(v)));
          O1[row*N + gn] = f2bf(sp);
        } else if constexpr (EPI == EPI_SPLIT_BF16) {
          if (gn < D_INNER) O1[row*D_INNER + gn] = f2bf(v);
          else              O2[row*D_INNER + (gn - D_INNER)] = f2bf(v);
        } else if constexpr (EPI == EPI_ACCUM_F32) {
          C[row*N + gn] += v;
        } else {
          C[row*N + gn] = v;
        }
      }
    }
  }
}

// ---------------- GLU GEMM fused with sigmoid gate: out = x + sigmoid(g)*v ----------------
__global__ __launch_bounds__(256, 2)
void gemm_glu(const unsigned short* __restrict__ A,      // xn_bf [ROWS][768]
              const unsigned short* __restrict__ B,      // Wglu_bf [1536][768]
              const float* __restrict__ bias,            // b_glu [1536]
              const float* __restrict__ x,               // residual [ROWS][768]
              float* __restrict__ out) {
  constexpr int LDT = 40;
  constexpr int K = D_MODEL;
  __shared__ unsigned short As[128*LDT];
  __shared__ unsigned short Bg[128*LDT];
  __shared__ unsigned short Bv[128*LDT];
  const int tid  = threadIdx.x;
  const int lane = tid & 63;
  const int wave = tid >> 6;
  const int wr = wave >> 1, wc = wave & 1;
  const int m0 = blockIdx.x * 128;
  const int n0 = blockIdx.y * 128;        // gate col base (0..640)
  const int srow = tid >> 2;
  const int scol = (tid & 3) * 8;

  f32x4 ag[4][4], av[4][4];
#pragma unroll
  for (int i = 0; i < 4; i++)
#pragma unroll
    for (int j = 0; j < 4; j++) { ag[i][j] = (f32x4){0,0,0,0}; av[i][j] = (f32x4){0,0,0,0}; }

  const int fr = lane & 15;
  const int fk = (lane >> 4) * 8;

  for (int k0 = 0; k0 < K; k0 += 32) {
    __syncthreads();
#pragma unroll
    for (int h = 0; h < 2; h++) {
      int r = srow + h*64;
      *reinterpret_cast<short8*>(&As[r*LDT + scol]) =
          *reinterpret_cast<const short8*>(A + (size_t)(m0 + r)*K + k0 + scol);
      *reinterpret_cast<short8*>(&Bg[r*LDT + scol]) =
          *reinterpret_cast<const short8*>(B + (size_t)(n0 + r)*K + k0 + scol);
      *reinterpret_cast<short8*>(&Bv[r*LDT + scol]) =
          *reinterpret_cast<const short8*>(B + (size_t)(n0 + D_MODEL + r)*K + k0 + scol);
    }
    __syncthreads();
    short8 aF[4], gF[4], vF[4];
#pragma unroll
    for (int mi = 0; mi < 4; mi++)
      aF[mi] = *reinterpret_cast<const short8*>(&As[(wr*64 + mi*16 + fr)*LDT + fk]);
#pragma unroll
    for (int ni = 0; ni < 4; ni++) {
      gF[ni] = *reinterpret_cast<const short8*>(&Bg[(wc*64 + ni*16 + fr)*LDT + fk]);
      vF[ni] = *reinterpret_cast<const short8*>(&Bv[(wc*64 + ni*16 + fr)*LDT + fk]);
    }
#pragma unroll
    for (int mi = 0; mi < 4; mi++)
#pragma unroll
      for (int ni = 0; ni < 4; ni++) {
        ag[mi][ni] = __builtin_amdgcn_mfma_f32_16x16x32_bf16(aF[mi], gF[ni], ag[mi][ni], 0, 0, 0);
        av[mi][ni] = __builtin_amdgcn_mfma_f32_16x16x32_bf16(aF[mi], vF[ni], av[mi][ni], 0, 0, 0);
      }
  }

  const int cr = (lane >> 4) * 4;
  const int cc = lane & 15;
#pragma unroll
  for (int mi = 0; mi < 4; mi++) {
#pragma unroll
    for (int ni = 0; ni < 4; ni++) {
      int gn = n0 + wc*64 + ni*16 + cc;
      int gmb = m0 + wr*64 + mi*16 + cr;
      float bg = bias[gn];
      float bv = bias[gn + D_MODEL];
#pragma unroll
      for (int j = 0; j < 4; j++) {
        float g = ag[mi][ni][j] + bg;
        float v = av[mi][ni][j] + bv;
        size_t idx = (size_t)(gmb + j)*D_MODEL + gn;
        out[idx] = x[idx] + v / (1.0f + __expf(-g));
      }
    }
  }
}

// ---------------- conv4 + SiLU (bf16 in -> bf16 u) ----------------
__global__ __launch_bounds__(256)
void conv_silu(const unsigned short* __restrict__ xm, const float* __restrict__ cw,
               const float* __restrict__ cb, unsigned short* __restrict__ u_bf) {
  int idx = blockIdx.x * blockDim.x + threadIdx.x;
  if (idx >= ROWS * D_INNER) return;
  int d   = idx % D_INNER;
  int row = idx / D_INNER;        // b*SEQ + l
  int l   = row % SEQ;
  float acc = cb[d];
#pragma unroll
  for (int k = 0; k < 4; k++) {
    int t = l - 3 + k;
    if (t >= 0) acc += cw[d*4 + k] * bf2f(xm[(size_t)(row - 3 + k)*D_INNER + d]);
  }
  float s  = 1.0f / (1.0f + __expf(-acc));
  u_bf[idx] = f2bf(acc * s);
}

// ================= chunked selective scan =================
// LDS-staged (bulk coalesced loads, amortized over 16 steps) + transposed
// [.][t] layouts (rows padded to 20 floats) so fragment reads are
// ds_read_b128 over 4 timesteps; n-reduction via DPP (VALU pipe).

// Phase 1: per-(b,d,n,chunk) affine composition: P = prod(a), q = zero-state response.
__global__ __launch_bounds__(256)
void scan_part1(const unsigned short* __restrict__ dt_bf,
                const unsigned short* __restrict__ u_bf,
                const float* __restrict__ xdbl, const float* __restrict__ A_log,
                float* __restrict__ Pv, float* __restrict__ Qv) {
  __shared__ __align__(16) float dt_s[16][20];   // [d][t]
  __shared__ __align__(16) float u_s[16][20];    // [d][t]
  __shared__ __align__(16) float b_s[16][20];    // [n][t]
  const int tid  = threadIdx.x;
  const int lane = tid & 63;
  const int wv   = tid >> 6;
  const int b    = blockIdx.y;
  const int c    = blockIdx.z;
  const int d0   = blockIdx.x * 16;
  const int dl   = wv*4 + (lane >> 4);   // channel within block
  const int n    = lane & 15;            // state index
  const int d    = d0 + dl;
  const float Aa = -__expf(A_log[d*D_STATE + n]);
  float P = 1.f, q = 0.f;
  const size_t rowbase = (size_t)b * SEQ + (size_t)c * CHUNK;
  const int si = tid >> 4, sj = tid & 15;   // si = t, sj = d (or n)

  for (int t0 = 0; t0 < CHUNK; t0 += 16) {
    __syncthreads();
    {
      size_t r = (rowbase + t0 + si) * D_INNER + d0 + sj;
      dt_s[sj][si] = bf2f(dt_bf[r]);
      u_s[sj][si]  = bf2f(u_bf[r]);
      b_s[sj][si]  = xdbl[(rowbase + t0 + si)*80 + DT_RANK + sj];
    }
    __syncthreads();
#pragma unroll
    for (int q4 = 0; q4 < 4; q4++) {
      f32x4 dtq = *reinterpret_cast<const f32x4*>(&dt_s[dl][q4*4]);
      f32x4 uq  = *reinterpret_cast<const f32x4*>(&u_s[dl][q4*4]);
      f32x4 Bq  = *reinterpret_cast<const f32x4*>(&b_s[n][q4*4]);
#pragma unroll
      for (int i = 0; i < 4; i++) {
        float dtv = dtq[i];
        float a   = __expf(dtv * Aa);
        q = fmaf(a, q, dtv * uq[i] * Bq[i]);
        P *= a;
      }
    }
  }
  size_t idx = (((size_t)b*D_INNER + d)*D_STATE + n)*NCHUNK + c;
  Pv[idx] = P;
  Qv[idx] = q;
}

// Phase 2: sequential combine across chunks -> initial state per chunk.
__global__ __launch_bounds__(256)
void scan_combine(const float* __restrict__ Pv, const float* __restrict__ Qv,
                  float* __restrict__ H0) {
  int idx = blockIdx.x * 256 + threadIdx.x;   // (b,d,n)
  if (idx >= BATCH*D_INNER*D_STATE) return;
  float h = 0.f;
  size_t base = (size_t)idx * NCHUNK;
#pragma unroll
  for (int c = 0; c < NCHUNK; c++) {
    H0[base + c] = h;
    h = fmaf(Pv[base + c], h, Qv[base + c]);
  }
}

// Phase 3: re-walk each chunk from its initial state; y + gating fused.
__global__ __launch_bounds__(256)
void scan_part3(const unsigned short* __restrict__ dt_bf,
                const unsigned short* __restrict__ u_bf,
                const unsigned short* __restrict__ z_bf,
                const float* __restrict__ xdbl, const float* __restrict__ A_log,
                const float* __restrict__ Dp, const float* __restrict__ H0,
                unsigned short* __restrict__ y_bf) {
  __shared__ __align__(16) float dt_s[16][20];   // [d][t]
  __shared__ __align__(16) float u_s[16][20];    // [d][t]
  __shared__ __align__(16) float z_s[16][20];    // [d][t]
  __shared__ __align__(16) float bc_s[32][20];   // [B: n][t], [C: 16+n][t]
  const int tid  = threadIdx.x;
  const int lane = tid & 63;
  const int wv   = tid >> 6;
  const int b    = blockIdx.y;
  const int c    = blockIdx.z;
  const int d0   = blockIdx.x * 16;
  const int dl   = wv*4 + (lane >> 4);
  const int n    = lane & 15;
  const int d    = d0 + dl;
  const float Aa = -__expf(A_log[d*D_STATE + n]);
  const float Dd = Dp[d];
  float h = H0[(((size_t)b*D_INNER + d)*D_STATE + n)*NCHUNK + c];
  const size_t rowbase = (size_t)b * SEQ + (size_t)c * CHUNK;
  const int si = tid >> 4, sj = tid & 15;

  for (int t0 = 0; t0 < CHUNK; t0 += 16) {
    __syncthreads();
    {
      size_t r = (rowbase + t0 + si) * D_INNER + d0 + sj;
      dt_s[sj][si] = bf2f(dt_bf[r]);
      u_s[sj][si]  = bf2f(u_bf[r]);
      z_s[sj][si]  = bf2f(z_bf[r]);
      const f32x2 p = *reinterpret_cast<const f32x2*>(&xdbl[(rowbase + t0 + si)*80 + DT_RANK + sj*2]);
      bc_s[sj*2][si]   = p[0];
      bc_s[sj*2+1][si] = p[1];
    }
    __syncthreads();
#pragma unroll
    for (int q4 = 0; q4 < 4; q4++) {
      f32x4 dtq = *reinterpret_cast<const f32x4*>(&dt_s[dl][q4*4]);
      f32x4 uq  = *reinterpret_cast<const f32x4*>(&u_s[dl][q4*4]);
      f32x4 zq  = *reinterpret_cast<const f32x4*>(&z_s[dl][q4*4]);
      f32x4 Bq  = *reinterpret_cast<const f32x4*>(&bc_s[n][q4*4]);
      f32x4 Cq  = *reinterpret_cast<const f32x4*>(&bc_s[16+n][q4*4]);
#pragma unroll
      for (int i = 0; i < 4; i++) {
        float dtv = dtq[i];
        float dA  = __expf(dtv * Aa);
        h = fmaf(dA, h, dtv*uq[i]*Bq[i]);
        float y = reduce16(h * Cq[i]);
        if (n == 0) {
          float z  = zq[i];
          float sz = z / (1.0f + __expf(-z));
          float yv = (y + uq[i] * Dd) * sz;
          y_bf[(rowbase + t0 + q4*4 + i)*D_INNER + d] = f2bf(yv);
        }
      }
    }
  }
}

extern "C" void kernel_launch(void* const* d_in, const int* in_sizes, int n_in,
                              void* d_out, int out_size, void* d_ws, size_t ws_size,
                              hipStream_t stream) {
  const float* x      = (const float*)d_in[0];
  const float* lng    = (const float*)d_in[1];
  const float* lnb    = (const float*)d_in[2];
  const float* W_in   = (const float*)d_in[3];
  const float* conv_w = (const float*)d_in[4];
  const float* conv_b = (const float*)d_in[5];
  const float* W_x    = (const float*)d_in[6];
  const float* W_dt   = (const float*)d_in[7];
  const float* b_dt   = (const float*)d_in[8];
  const float* A_log  = (const float*)d_in[9];
  const float* Dp     = (const float*)d_in[10];
  const float* W_out  = (const float*)d_in[11];
  const float* W_glu  = (const float*)d_in[12];
  const float* b_glu  = (const float*)d_in[13];
  float* out = (float*)d_out;

  char* ws = (char*)d_ws;
  size_t off = 0;
  auto alloc = [&](size_t bytes) -> void* {
    void* p = ws + off; off += (bytes + 255) & ~(size_t)255; return p;
  };
  unsigned short* xn_bf   = (unsigned short*)alloc((size_t)ROWS*D_MODEL*2);
  unsigned short* Win_bf  = (unsigned short*)alloc((size_t)2*D_INNER*D_MODEL*2);
  unsigned short* Wx_bf   = (unsigned short*)alloc((size_t)80*D_INNER*2);
  unsigned short* Wdt_bf  = (unsigned short*)alloc((size_t)D_INNER*64*2);
  unsigned short* Wout_bf = (unsigned short*)alloc((size_t)D_MODEL*D_INNER*2);
  unsigned short* Wglu_bf = (unsigned short*)alloc((size_t)2*D_MODEL*D_MODEL*2);
  unsigned short* xm_bf   = (unsigned short*)alloc((size_t)ROWS*D_INNER*2);  // reused as dt_bf
  unsigned short* z_bf    = (unsigned short*)alloc((size_t)ROWS*D_INNER*2);
  unsigned short* u_bf    = (unsigned short*)alloc((size_t)ROWS*D_INNER*2);
  float* x_dbl            = (float*)alloc((size_t)ROWS*80*4);
  unsigned short* dtlo_bf = (unsigned short*)alloc((size_t)ROWS*64*2);
  unsigned short* y_bf    = (unsigned short*)alloc((size_t)ROWS*D_INNER*2);
  float* Pv               = (float*)alloc((size_t)BATCH*D_INNER*D_STATE*NCHUNK*4);
  float* Qv               = (float*)alloc((size_t)BATCH*D_INNER*D_STATE*NCHUNK*4);
  float* H0               = (float*)alloc((size_t)BATCH*D_INNER*D_STATE*NCHUNK*4);
  unsigned short* dt_bf   = xm_bf;   // xm dead after conv_silu; dt born later

  if (off > ws_size) return;  // workspace too small -> clean absmax failure, not a fault

  int n1 = 2*D_INNER*D_MODEL;
  cast_bf<<<(n1+255)/256, 256, 0, stream>>>(W_in, Win_bf, n1);
  int n2 = 80*D_INNER;
  cast_bf<<<(n2+255)/256, 256, 0, stream>>>(W_x, Wx_bf, n2);
  cast_wdt<<<(D_INNER*64+255)/256, 256, 0, stream>>>(W_dt, Wdt_bf);
  int n3 = D_MODEL*D_INNER;
  cast_bf<<<(n3+255)/256, 256, 0, stream>>>(W_out, Wout_bf, n3);
  int n4 = 2*D_MODEL*D_MODEL;
  cast_bf<<<(n4+255)/256, 256, 0, stream>>>(W_glu, Wglu_bf, n4);

  ln_kernel<<<ROWS/4, 256, 0, stream>>>(x, lng, lnb, xn_bf);

  // xz = xn @ W_in^T   (8192 x 3072 x 768) -> split bf16 xm / z
  gemm_bt<EPI_SPLIT_BF16><<<dim3(ROWS/128, (2*D_INNER)/128), 256, 0, stream>>>(
      xn_bf, Win_bf, nullptr, xm_bf, z_bf, nullptr, ROWS, 2*D_INNER, D_MODEL);

  int tc = ROWS*D_INNER;
  conv_silu<<<(tc+255)/256, 256, 0, stream>>>(xm_bf, conv_w, conv_b, u_bf);

  // x_dbl = u @ W_x^T   (8192 x 80 x 1536)
  gemm_bt<EPI_STORE_F32><<<dim3(ROWS/128, 1), 256, 0, stream>>>(
      u_bf, Wx_bf, x_dbl, nullptr, nullptr, nullptr, ROWS, 80, D_INNER);

  cast_dtlo<<<(ROWS*64+255)/256, 256, 0, stream>>>(x_dbl, dtlo_bf);

  // dt = softplus(dt_lo @ W_dt^T + b_dt) -> bf16 (into dead xm region)
  gemm_bt<EPI_SOFTPLUS_BF16><<<dim3(ROWS/128, D_INNER/128), 256, 0, stream>>>(
      dtlo_bf, Wdt_bf, nullptr, dt_bf, nullptr, b_dt, ROWS, D_INNER, 64);

  // chunked scan
  scan_part1<<<dim3(D_INNER/16, BATCH, NCHUNK), 256, 0, stream>>>(
      dt_bf, u_bf, x_dbl, A_log, Pv, Qv);
  scan_combine<<<(BATCH*D_INNER*D_STATE + 255)/256, 256, 0, stream>>>(Pv, Qv, H0);
  scan_part3<<<dim3(D_INNER/16, BATCH, NCHUNK), 256, 0, stream>>>(
      dt_bf, u_bf, z_bf, x_dbl, A_log, Dp, H0, y_bf);

  // out = x + sigmoid(gate)*value   (fused GLU GEMM, 8192 x 768(x2) x 768)
  gemm_glu<<<dim3(ROWS/128, D_MODEL/128), 256, 0, stream>>>(
      xn_bf, Wglu_bf, b_glu, x, out);

  // out += y @ W_out^T   (8192 x 768 x 1536)
  gemm_bt<EPI_ACCUM_F32><<<dim3(ROWS/128, D_MODEL/128), 256, 0, stream>>>(
      y_bf, Wout_bf, out, nullptr, nullptr, nullptr, ROWS, D_MODEL, D_INNER);
}

// Round 6
// 418.473 us; speedup vs baseline: 1.9441x; 1.3295x over previous
//
#include <hip/hip_runtime.h>
#include <hip/hip_bf16.h>

#define D_MODEL 768
#define D_STATE 16
#define D_INNER 1536
#define DT_RANK 48
#define BATCH   4
#define SEQ     2048
#define ROWS    (BATCH*SEQ)   // 8192
#define NCHUNK  8
#define CHUNK   (SEQ/NCHUNK)  // 256

typedef __attribute__((ext_vector_type(8)))  short  short8;
typedef __attribute__((ext_vector_type(4)))  float  f32x4;
typedef __attribute__((ext_vector_type(2)))  float  f32x2;
typedef __attribute__((ext_vector_type(4)))  unsigned short us4;

static __device__ __forceinline__ unsigned short f2bf(float f) {
  union { float f; unsigned u; } v; v.f = f;
  unsigned r = v.u + 0x7fffu + ((v.u >> 16) & 1u);
  return (unsigned short)(r >> 16);
}
static __device__ __forceinline__ float bf2f(unsigned short u) {
  union { unsigned u; float f; } v; v.u = ((unsigned)u) << 16;
  return v.f;
}

// async global->LDS, 16B per lane. LDS dest is wave-uniform base + lane*16.
static __device__ __forceinline__ void gl2lds16(const unsigned short* g, unsigned short* l) {
  __builtin_amdgcn_global_load_lds(
      (const __attribute__((address_space(1))) unsigned int*)g,
      (__attribute__((address_space(3))) unsigned int*)l, 16, 0, 0);
}

// DPP-based add of lane-permuted value (VALU pipe, no LDS traffic)
template<int CTRL>
static __device__ __forceinline__ float dpp_add(float x) {
  union { float f; int i; } v; v.f = x;
  int m = __builtin_amdgcn_update_dpp(0, v.i, CTRL, 0xF, 0xF, true);
  union { int i; float f; } r; r.i = m;
  return x + r.f;
}
// sum over each 16-lane group (n = lane & 15)
static __device__ __forceinline__ float reduce16(float y) {
  y = dpp_add<0xB1>(y);   // quad_perm [1,0,3,2]
  y = dpp_add<0x4E>(y);   // quad_perm [2,3,0,1]
  y = dpp_add<0x141>(y);  // row_half_mirror
  y = dpp_add<0x140>(y);  // row_mirror
  return y;
}

// ---------------- LayerNorm -> bf16 ----------------
__global__ __launch_bounds__(256)
void ln_kernel(const float* __restrict__ x, const float* __restrict__ gamma,
               const float* __restrict__ beta, unsigned short* __restrict__ xn_bf) {
  int row  = blockIdx.x * 4 + (threadIdx.x >> 6);
  int lane = threadIdx.x & 63;
  const float* xr = x + (size_t)row * D_MODEL;
  f32x4 v[3];
  float s = 0.f, s2 = 0.f;
#pragma unroll
  for (int c = 0; c < 3; c++) {
    v[c] = *reinterpret_cast<const f32x4*>(&xr[c*256 + lane*4]);
#pragma unroll
    for (int i = 0; i < 4; i++) { s += v[c][i]; s2 += v[c][i]*v[c][i]; }
  }
#pragma unroll
  for (int off = 1; off < 64; off <<= 1) {
    s  += __shfl_xor(s,  off);
    s2 += __shfl_xor(s2, off);
  }
  float mu   = s * (1.0f/768.0f);
  float var  = s2 * (1.0f/768.0f) - mu*mu;
  float rstd = rsqrtf(var + 1e-5f);
#pragma unroll
  for (int c = 0; c < 3; c++) {
    us4 o;
#pragma unroll
    for (int i = 0; i < 4; i++) {
      int g = c*256 + lane*4 + i;
      float xn = (v[c][i]-mu)*rstd*gamma[g] + beta[g];
      o[i] = f2bf(xn);
    }
    *reinterpret_cast<us4*>(&xn_bf[(size_t)row*D_MODEL + c*256 + lane*4]) = o;
  }
}

// ---------------- casts / zero ----------------
__global__ void cast_bf(const float* __restrict__ in, unsigned short* __restrict__ out, int n) {
  int i = blockIdx.x * blockDim.x + threadIdx.x;
  if (i < n) out[i] = f2bf(in[i]);
}
__global__ void zero_f32(float* __restrict__ p, int n) {
  int i = blockIdx.x * blockDim.x + threadIdx.x;
  if (i < n) p[i] = 0.f;
}
__global__ void cast_wdt(const float* __restrict__ wdt, unsigned short* __restrict__ out) {
  int i = blockIdx.x * blockDim.x + threadIdx.x;
  if (i >= D_INNER*64) return;
  int r = i >> 6, c = i & 63;
  out[i] = (c < DT_RANK) ? f2bf(wdt[r*DT_RANK + c]) : (unsigned short)0;
}
__global__ void cast_dtlo(const float* __restrict__ xdbl, unsigned short* __restrict__ out) {
  int i = blockIdx.x * blockDim.x + threadIdx.x;
  if (i >= ROWS*64) return;
  int r = i >> 6, c = i & 63;
  out[i] = (c < DT_RANK) ? f2bf(xdbl[(size_t)r*80 + c]) : (unsigned short)0;
}

// ---------------- GEMM: C[M,N] = A[M,K] @ B[N,K]^T  (bf16 in) ----------------
// Staging: global_load_lds width-16 into linear [128][32] LDS tiles with
// both-sides slot swizzle  slot = (lane&3) ^ f(row&15), f(r) = (r + r>>2) & 3.
#define EPI_STORE_F32     0
#define EPI_SOFTPLUS_BF16 1
#define EPI_ACCUM_F32     2
#define EPI_SPLIT_BF16    3
#define EPI_ATOMIC_F32    4

template<int EPI>
__global__ __launch_bounds__(256, 2)
void gemm_bt(const unsigned short* __restrict__ A,
             const unsigned short* __restrict__ B,
             float* __restrict__ C,
             unsigned short* __restrict__ O1,
             unsigned short* __restrict__ O2,
             const float* __restrict__ bias,
             int M, int N, int K) {
  __shared__ unsigned short As[128*32];
  __shared__ unsigned short Bs[128*32];
  const int tid  = threadIdx.x;
  const int lane = tid & 63;
  const int wave = tid >> 6;
  const int wr = wave >> 1, wc = wave & 1;
  const int m0 = blockIdx.x * 128;
  const int n0 = blockIdx.y * 128;

  // staging source (per-lane, inverse-swizzled)
  const int sr  = lane >> 2;                              // row in 16-row window
  const int ssl = (lane & 3) ^ ((sr + (sr >> 2)) & 3);    // swizzled col slot
  const unsigned short* gA0 = A + (size_t)(m0 + wave*32 + sr)*K + ssl*8;
  const unsigned short* gA1 = gA0 + (size_t)16*K;
  const unsigned short* gB0 = B + (size_t)(n0 + wave*32 + sr)*K + ssl*8;
  const unsigned short* gB1 = gB0 + (size_t)16*K;
  unsigned short* lA0 = &As[(wave*32)*32];
  unsigned short* lA1 = &As[(wave*32 + 16)*32];
  unsigned short* lB0 = &Bs[(wave*32)*32];
  unsigned short* lB1 = &Bs[(wave*32 + 16)*32];

  f32x4 acc[4][4];
#pragma unroll
  for (int i = 0; i < 4; i++)
#pragma unroll
    for (int j = 0; j < 4; j++) acc[i][j] = (f32x4){0.f,0.f,0.f,0.f};

  // fragment read offsets (swizzled), loop-invariant
  const int ffr = lane & 15;
  const int fc  = lane >> 4;
  const int fsl = (fc ^ ((ffr + (ffr >> 2)) & 3)) * 8;
  int aoff[4], boff[4];
#pragma unroll
  for (int i = 0; i < 4; i++) {
    aoff[i] = (wr*64 + i*16 + ffr)*32 + fsl;
    boff[i] = (wc*64 + i*16 + ffr)*32 + fsl;
  }

  const int kslice = K / gridDim.z;
  const int kb = blockIdx.z * kslice;
  const int ke = kb + kslice;

  for (int k0 = kb; k0 < ke; k0 += 32) {
    __syncthreads();                    // prior reads done before overwrite
    gl2lds16(gA0 + k0, lA0);
    gl2lds16(gA1 + k0, lA1);
    gl2lds16(gB0 + k0, lB0);
    gl2lds16(gB1 + k0, lB1);
    __syncthreads();                    // drains vmcnt -> tiles visible
    short8 aF[4], bF[4];
#pragma unroll
    for (int mi = 0; mi < 4; mi++)
      aF[mi] = *reinterpret_cast<const short8*>(&As[aoff[mi]]);
#pragma unroll
    for (int ni = 0; ni < 4; ni++)
      bF[ni] = *reinterpret_cast<const short8*>(&Bs[boff[ni]]);
#pragma unroll
    for (int mi = 0; mi < 4; mi++)
#pragma unroll
      for (int ni = 0; ni < 4; ni++)
        acc[mi][ni] = __builtin_amdgcn_mfma_f32_16x16x32_bf16(aF[mi], bF[ni], acc[mi][ni], 0, 0, 0);
  }

  const int cr = (lane >> 4) * 4;
  const int cc = lane & 15;
#pragma unroll
  for (int mi = 0; mi < 4; mi++) {
#pragma unroll
    for (int ni = 0; ni < 4; ni++) {
      int gn = n0 + wc*64 + ni*16 + cc;
      if (gn >= N) continue;
      int gmb = m0 + wr*64 + mi*16 + cr;
#pragma unroll
      for (int j = 0; j < 4; j++) {
        float v = acc[mi][ni][j];
        size_t row = (size_t)(gmb + j);
        if constexpr (EPI == EPI_SOFTPLUS_BF16) {
          v += bias[gn];
          float sp = fmaxf(v, 0.0f) + log1pf(expf(-fabsf(v)));
          O1[row*N + gn] = f2bf(sp);
        } else if constexpr (EPI == EPI_SPLIT_BF16) {
          if (gn < D_INNER) O1[row*D_INNER + gn] = f2bf(v);
          else              O2[row*D_INNER + (gn - D_INNER)] = f2bf(v);
        } else if constexpr (EPI == EPI_ACCUM_F32) {
          C[row*N + gn] += v;
        } else if constexpr (EPI == EPI_ATOMIC_F32) {
          atomicAdd(&C[row*N + gn], v);
        } else {
          C[row*N + gn] = v;
        }
      }
    }
  }
}

// ---------------- GLU GEMM fused with sigmoid gate ----------------
__global__ __launch_bounds__(256, 2)
void gemm_glu(const unsigned short* __restrict__ A,      // xn_bf [ROWS][768]
              const unsigned short* __restrict__ B,      // Wglu_bf [1536][768]
              const float* __restrict__ bias,
              const float* __restrict__ x,
              float* __restrict__ out) {
  constexpr int K = D_MODEL;
  __shared__ unsigned short As[128*32];
  __shared__ unsigned short Bg[128*32];
  __shared__ unsigned short Bv[128*32];
  const int tid  = threadIdx.x;
  const int lane = tid & 63;
  const int wave = tid >> 6;
  const int wr = wave >> 1, wc = wave & 1;
  const int m0 = blockIdx.x * 128;
  const int n0 = blockIdx.y * 128;

  const int sr  = lane >> 2;
  const int ssl = (lane & 3) ^ ((sr + (sr >> 2)) & 3);
  const unsigned short* gA0 = A + (size_t)(m0 + wave*32 + sr)*K + ssl*8;
  const unsigned short* gG0 = B + (size_t)(n0 + wave*32 + sr)*K + ssl*8;
  const unsigned short* gV0 = B + (size_t)(n0 + D_MODEL + wave*32 + sr)*K + ssl*8;
  unsigned short* lA0 = &As[(wave*32)*32];
  unsigned short* lA1 = &As[(wave*32 + 16)*32];
  unsigned short* lG0 = &Bg[(wave*32)*32];
  unsigned short* lG1 = &Bg[(wave*32 + 16)*32];
  unsigned short* lV0 = &Bv[(wave*32)*32];
  unsigned short* lV1 = &Bv[(wave*32 + 16)*32];

  f32x4 ag[4][4], av[4][4];
#pragma unroll
  for (int i = 0; i < 4; i++)
#pragma unroll
    for (int j = 0; j < 4; j++) { ag[i][j] = (f32x4){0,0,0,0}; av[i][j] = (f32x4){0,0,0,0}; }

  const int ffr = lane & 15;
  const int fc  = lane >> 4;
  const int fsl = (fc ^ ((ffr + (ffr >> 2)) & 3)) * 8;
  int aoff[4], boff[4];
#pragma unroll
  for (int i = 0; i < 4; i++) {
    aoff[i] = (wr*64 + i*16 + ffr)*32 + fsl;
    boff[i] = (wc*64 + i*16 + ffr)*32 + fsl;
  }

  for (int k0 = 0; k0 < K; k0 += 32) {
    __syncthreads();
    gl2lds16(gA0 + k0, lA0);
    gl2lds16(gA0 + 16*K + k0, lA1);
    gl2lds16(gG0 + k0, lG0);
    gl2lds16(gG0 + 16*K + k0, lG1);
    gl2lds16(gV0 + k0, lV0);
    gl2lds16(gV0 + 16*K + k0, lV1);
    __syncthreads();
    short8 aF[4], gF[4], vF[4];
#pragma unroll
    for (int mi = 0; mi < 4; mi++)
      aF[mi] = *reinterpret_cast<const short8*>(&As[aoff[mi]]);
#pragma unroll
    for (int ni = 0; ni < 4; ni++) {
      gF[ni] = *reinterpret_cast<const short8*>(&Bg[boff[ni]]);
      vF[ni] = *reinterpret_cast<const short8*>(&Bv[boff[ni]]);
    }
#pragma unroll
    for (int mi = 0; mi < 4; mi++)
#pragma unroll
      for (int ni = 0; ni < 4; ni++) {
        ag[mi][ni] = __builtin_amdgcn_mfma_f32_16x16x32_bf16(aF[mi], gF[ni], ag[mi][ni], 0, 0, 0);
        av[mi][ni] = __builtin_amdgcn_mfma_f32_16x16x32_bf16(aF[mi], vF[ni], av[mi][ni], 0, 0, 0);
      }
  }

  const int cr = (lane >> 4) * 4;
  const int cc = lane & 15;
#pragma unroll
  for (int mi = 0; mi < 4; mi++) {
#pragma unroll
    for (int ni = 0; ni < 4; ni++) {
      int gn = n0 + wc*64 + ni*16 + cc;
      int gmb = m0 + wr*64 + mi*16 + cr;
      float bg = bias[gn];
      float bv = bias[gn + D_MODEL];
#pragma unroll
      for (int j = 0; j < 4; j++) {
        float g = ag[mi][ni][j] + bg;
        float v = av[mi][ni][j] + bv;
        size_t idx = (size_t)(gmb + j)*D_MODEL + gn;
        out[idx] = x[idx] + v / (1.0f + __expf(-g));
      }
    }
  }
}

// ---------------- conv4 + SiLU ----------------
__global__ __launch_bounds__(256)
void conv_silu(const unsigned short* __restrict__ xm, const float* __restrict__ cw,
               const float* __restrict__ cb, unsigned short* __restrict__ u_bf) {
  int idx = blockIdx.x * blockDim.x + threadIdx.x;
  if (idx >= ROWS * D_INNER) return;
  int d   = idx % D_INNER;
  int row = idx / D_INNER;
  int l   = row % SEQ;
  float acc = cb[d];
#pragma unroll
  for (int k = 0; k < 4; k++) {
    int t = l - 3 + k;
    if (t >= 0) acc += cw[d*4 + k] * bf2f(xm[(size_t)(row - 3 + k)*D_INNER + d]);
  }
  float s  = 1.0f / (1.0f + __expf(-acc));
  u_bf[idx] = f2bf(acc * s);
}

// ================= chunked selective scan =================
// Phase 1: per-(b,d,n,chunk) affine composition.
__global__ __launch_bounds__(256)
void scan_part1(const unsigned short* __restrict__ dt_bf,
                const unsigned short* __restrict__ u_bf,
                const float* __restrict__ xdbl, const float* __restrict__ A_log,
                float* __restrict__ Pv, float* __restrict__ Qv) {
  __shared__ __align__(16) float dt_s[16][20];   // [d][t]
  __shared__ __align__(16) float du_s[16][20];   // dt*u
  __shared__ __align__(16) float b_s[16][20];    // [n][t]
  const int tid  = threadIdx.x;
  const int lane = tid & 63;
  const int wv   = tid >> 6;
  const int b    = blockIdx.y;
  const int c    = blockIdx.z;
  const int d0   = blockIdx.x * 16;
  const int dl   = wv*4 + (lane >> 4);
  const int n    = lane & 15;
  const int d    = d0 + dl;
  const float Aa = -__expf(A_log[d*D_STATE + n]);
  float P = 1.f, q = 0.f;
  const size_t rowbase = (size_t)b * SEQ + (size_t)c * CHUNK;
  const int si = tid >> 4, sj = tid & 15;

  for (int t0 = 0; t0 < CHUNK; t0 += 16) {
    __syncthreads();
    {
      size_t r = (rowbase + t0 + si) * D_INNER + d0 + sj;
      float dtv = bf2f(dt_bf[r]);
      float uv  = bf2f(u_bf[r]);
      dt_s[sj][si] = dtv;
      du_s[sj][si] = dtv * uv;
      b_s[sj][si]  = xdbl[(rowbase + t0 + si)*80 + DT_RANK + sj];
    }
    __syncthreads();
#pragma unroll
    for (int q4 = 0; q4 < 4; q4++) {
      f32x4 dtq = *reinterpret_cast<const f32x4*>(&dt_s[dl][q4*4]);
      f32x4 duq = *reinterpret_cast<const f32x4*>(&du_s[dl][q4*4]);
      f32x4 Bq  = *reinterpret_cast<const f32x4*>(&b_s[n][q4*4]);
#pragma unroll
      for (int i = 0; i < 4; i++) {
        float a = __expf(dtq[i] * Aa);
        q = fmaf(a, q, duq[i] * Bq[i]);
        P *= a;
      }
    }
  }
  size_t idx = (((size_t)b*D_INNER + d)*D_STATE + n)*NCHUNK + c;
  Pv[idx] = P;
  Qv[idx] = q;
}

// Phase 2: sequential combine across chunks.
__global__ __launch_bounds__(256)
void scan_combine(const float* __restrict__ Pv, const float* __restrict__ Qv,
                  float* __restrict__ H0) {
  int idx = blockIdx.x * 256 + threadIdx.x;
  if (idx >= BATCH*D_INNER*D_STATE) return;
  float h = 0.f;
  size_t base = (size_t)idx * NCHUNK;
#pragma unroll
  for (int c = 0; c < NCHUNK; c++) {
    H0[base + c] = h;
    h = fmaf(Pv[base + c], h, Qv[base + c]);
  }
}

// Phase 3: re-walk each chunk; y staged to LDS, batch gating per 16 steps.
__global__ __launch_bounds__(256)
void scan_part3(const unsigned short* __restrict__ dt_bf,
                const unsigned short* __restrict__ u_bf,
                const unsigned short* __restrict__ z_bf,
                const float* __restrict__ xdbl, const float* __restrict__ A_log,
                const float* __restrict__ Dp, const float* __restrict__ H0,
                unsigned short* __restrict__ y_bf) {
  __shared__ __align__(16) float dt_s[16][20];   // [d][t]
  __shared__ __align__(16) float du_s[16][20];   // dt*u
  __shared__ __align__(16) float uD_s[16][20];   // u*D
  __shared__ __align__(16) float bc_s[32][20];   // B:[n][t], C:[16+n][t]
  __shared__ float y_s[16][17];                  // [d][t]
  const int tid  = threadIdx.x;
  const int lane = tid & 63;
  const int wv   = tid >> 6;
  const int b    = blockIdx.y;
  const int c    = blockIdx.z;
  const int d0   = blockIdx.x * 16;
  const int dl   = wv*4 + (lane >> 4);
  const int n    = lane & 15;
  const int d    = d0 + dl;
  const float Aa = -__expf(A_log[d*D_STATE + n]);
  float h = H0[(((size_t)b*D_INNER + d)*D_STATE + n)*NCHUNK + c];
  const size_t rowbase = (size_t)b * SEQ + (size_t)c * CHUNK;
  const int si = tid >> 4, sj = tid & 15;
  const float Dstage = Dp[d0 + sj];

  for (int t0 = 0; t0 < CHUNK; t0 += 16) {
    __syncthreads();
    {
      size_t r = (rowbase + t0 + si) * D_INNER + d0 + sj;
      float dtv = bf2f(dt_bf[r]);
      float uv  = bf2f(u_bf[r]);
      dt_s[sj][si] = dtv;
      du_s[sj][si] = dtv * uv;
      uD_s[sj][si] = uv * Dstage;
      const f32x2 p = *reinterpret_cast<const f32x2*>(&xdbl[(rowbase + t0 + si)*80 + DT_RANK + sj*2]);
      bc_s[sj*2][si]   = p[0];
      bc_s[sj*2+1][si] = p[1];
    }
    __syncthreads();
#pragma unroll
    for (int q4 = 0; q4 < 4; q4++) {
      f32x4 dtq = *reinterpret_cast<const f32x4*>(&dt_s[dl][q4*4]);
      f32x4 duq = *reinterpret_cast<const f32x4*>(&du_s[dl][q4*4]);
      f32x4 Bq  = *reinterpret_cast<const f32x4*>(&bc_s[n][q4*4]);
      f32x4 Cq  = *reinterpret_cast<const f32x4*>(&bc_s[16+n][q4*4]);
#pragma unroll
      for (int i = 0; i < 4; i++) {
        float dA = __expf(dtq[i] * Aa);
        h = fmaf(dA, h, duq[i] * Bq[i]);
        float y = reduce16(h * Cq[i]);
        if (n == 0) y_s[dl][q4*4 + i] = y;
      }
    }
    __syncthreads();
    {  // batch gating: thread (si=t, sj=d)
      size_t row = rowbase + t0 + si;
      float y  = y_s[sj][si];
      float z  = bf2f(z_bf[row*D_INNER + d0 + sj]);
      float sz = z / (1.0f + __expf(-z));
      float yv = (y + uD_s[sj][si]) * sz;
      y_bf[row*D_INNER + d0 + sj] = f2bf(yv);
    }
  }
}

extern "C" void kernel_launch(void* const* d_in, const int* in_sizes, int n_in,
                              void* d_out, int out_size, void* d_ws, size_t ws_size,
                              hipStream_t stream) {
  const float* x      = (const float*)d_in[0];
  const float* lng    = (const float*)d_in[1];
  const float* lnb    = (const float*)d_in[2];
  const float* W_in   = (const float*)d_in[3];
  const float* conv_w = (const float*)d_in[4];
  const float* conv_b = (const float*)d_in[5];
  const float* W_x    = (const float*)d_in[6];
  const float* W_dt   = (const float*)d_in[7];
  const float* b_dt   = (const float*)d_in[8];
  const float* A_log  = (const float*)d_in[9];
  const float* Dp     = (const float*)d_in[10];
  const float* W_out  = (const float*)d_in[11];
  const float* W_glu  = (const float*)d_in[12];
  const float* b_glu  = (const float*)d_in[13];
  float* out = (float*)d_out;

  char* ws = (char*)d_ws;
  size_t off = 0;
  auto alloc = [&](size_t bytes) -> void* {
    void* p = ws + off; off += (bytes + 255) & ~(size_t)255; return p;
  };
  unsigned short* xn_bf   = (unsigned short*)alloc((size_t)ROWS*D_MODEL*2);
  unsigned short* Win_bf  = (unsigned short*)alloc((size_t)2*D_INNER*D_MODEL*2);
  unsigned short* Wx_bf   = (unsigned short*)alloc((size_t)128*D_INNER*2);  // 80 rows used, padded to 128
  unsigned short* Wdt_bf  = (unsigned short*)alloc((size_t)D_INNER*64*2);
  unsigned short* Wout_bf = (unsigned short*)alloc((size_t)D_MODEL*D_INNER*2);
  unsigned short* Wglu_bf = (unsigned short*)alloc((size_t)2*D_MODEL*D_MODEL*2);
  unsigned short* xm_bf   = (unsigned short*)alloc((size_t)ROWS*D_INNER*2);  // reused as dt_bf
  unsigned short* z_bf    = (unsigned short*)alloc((size_t)ROWS*D_INNER*2);
  unsigned short* u_bf    = (unsigned short*)alloc((size_t)ROWS*D_INNER*2);
  float* x_dbl            = (float*)alloc((size_t)ROWS*80*4);
  unsigned short* dtlo_bf = (unsigned short*)alloc((size_t)ROWS*64*2);
  unsigned short* y_bf    = (unsigned short*)alloc((size_t)ROWS*D_INNER*2);
  float* Pv               = (float*)alloc((size_t)BATCH*D_INNER*D_STATE*NCHUNK*4);
  float* Qv               = (float*)alloc((size_t)BATCH*D_INNER*D_STATE*NCHUNK*4);
  float* H0               = (float*)alloc((size_t)BATCH*D_INNER*D_STATE*NCHUNK*4);
  unsigned short* dt_bf   = xm_bf;   // xm dead after conv_silu; dt born later

  if (off > ws_size) return;

  int n1 = 2*D_INNER*D_MODEL;
  cast_bf<<<(n1+255)/256, 256, 0, stream>>>(W_in, Win_bf, n1);
  int n2 = 80*D_INNER;
  cast_bf<<<(n2+255)/256, 256, 0, stream>>>(W_x, Wx_bf, n2);
  cast_wdt<<<(D_INNER*64+255)/256, 256, 0, stream>>>(W_dt, Wdt_bf);
  int n3 = D_MODEL*D_INNER;
  cast_bf<<<(n3+255)/256, 256, 0, stream>>>(W_out, Wout_bf, n3);
  int n4 = 2*D_MODEL*D_MODEL;
  cast_bf<<<(n4+255)/256, 256, 0, stream>>>(W_glu, Wglu_bf, n4);
  zero_f32<<<(ROWS*80+255)/256, 256, 0, stream>>>(x_dbl, ROWS*80);

  ln_kernel<<<ROWS/4, 256, 0, stream>>>(x, lng, lnb, xn_bf);

  // xz = xn @ W_in^T   (8192 x 3072 x 768) -> split bf16 xm / z
  gemm_bt<EPI_SPLIT_BF16><<<dim3(ROWS/128, (2*D_INNER)/128), 256, 0, stream>>>(
      xn_bf, Win_bf, nullptr, xm_bf, z_bf, nullptr, ROWS, 2*D_INNER, D_MODEL);

  int tc = ROWS*D_INNER;
  conv_silu<<<(tc+255)/256, 256, 0, stream>>>(xm_bf, conv_w, conv_b, u_bf);

  // x_dbl = u @ W_x^T   (8192 x 80 x 1536), split-K=4 with atomics
  gemm_bt<EPI_ATOMIC_F32><<<dim3(ROWS/128, 1, 4), 256, 0, stream>>>(
      u_bf, Wx_bf, x_dbl, nullptr, nullptr, nullptr, ROWS, 80, D_INNER);

  cast_dtlo<<<(ROWS*64+255)/256, 256, 0, stream>>>(x_dbl, dtlo_bf);

  // dt = softplus(dt_lo @ W_dt^T + b_dt) -> bf16
  gemm_bt<EPI_SOFTPLUS_BF16><<<dim3(ROWS/128, D_INNER/128), 256, 0, stream>>>(
      dtlo_bf, Wdt_bf, nullptr, dt_bf, nullptr, b_dt, ROWS, D_INNER, 64);

  // chunked scan
  scan_part1<<<dim3(D_INNER/16, BATCH, NCHUNK), 256, 0, stream>>>(
      dt_bf, u_bf, x_dbl, A_log, Pv, Qv);
  scan_combine<<<(BATCH*D_INNER*D_STATE + 255)/256, 256, 0, stream>>>(Pv, Qv, H0);
  scan_part3<<<dim3(D_INNER/16, BATCH, NCHUNK), 256, 0, stream>>>(
      dt_bf, u_bf, z_bf, x_dbl, A_log, Dp, H0, y_bf);

  // out = x + sigmoid(gate)*value
  gemm_glu<<<dim3(ROWS/128, D_MODEL/128), 256, 0, stream>>>(
      xn_bf, Wglu_bf, b_glu, x, out);

  // out += y @ W_out^T
  gemm_bt<EPI_ACCUM_F32><<<dim3(ROWS/128, D_MODEL/128), 256, 0, stream>>>(
      y_bf, Wout_bf, out, nullptr, nullptr, nullptr, ROWS, D_MODEL, D_INNER);
}